// Round 1
// baseline (2129.398 us; speedup 1.0000x reference)
//
#include <hip/hip_runtime.h>

// LSTM net: linear1(20->50) -> 3x LSTMCell(50) with reference's buggy c-flow
//   -> linear2(50->8).  B=512, T=1024.
//
// Design: 256 blocks x 768 threads, 1 block / CU (2 batch elems per block,
// batch-interleaved as float2 everywhere).  Wave-specialized 3-stage pipeline
// over timesteps: at step s, L1 gates compute t=s, L2 gates t=s-1, L3 gates
// t=s-2, out-proj t=s-3.  Dependency check (with the bug c2 <- lstm3 cell):
//   L2(t) needs c2(t-1) = L3's cell from t-1, produced same step by the same
//   combine thread (L3 combine runs first) -> no extra barrier.
// Weights live in VGPRs (100 per gate thread); h-state broadcasts via LDS.
// linear1 fused into prefetch threads, 2 steps ahead, ring-3 xbuf.

#define T_SEQ 1024
#define HID   50
#define NGATE 200
#define IN_DIM 20
#define OUT_DIM 8

__device__ __forceinline__ float sigm(float x) {
    // 1/(1+e^-x); rcp approx ~1e-7 rel, fine vs 6e-4 threshold
    return __builtin_amdgcn_rcpf(1.0f + __expf(-x));
}
__device__ __forceinline__ float tanh_f(float x) {
    return fmaf(2.0f, sigm(2.0f * x), -1.0f);  // tanh = 2*sigm(2x)-1
}

__global__ __launch_bounds__(768, 3) void lstm_net_kernel(
    const float* __restrict__ x,
    const float* __restrict__ W1,   const float* __restrict__ b1,
    const float* __restrict__ Wih1, const float* __restrict__ Whh1,
    const float* __restrict__ bih1, const float* __restrict__ bhh1,
    const float* __restrict__ Wih2, const float* __restrict__ Whh2,
    const float* __restrict__ bih2, const float* __restrict__ bhh2,
    const float* __restrict__ Wih3, const float* __restrict__ Whh3,
    const float* __restrict__ bih3, const float* __restrict__ bhh3,
    const float* __restrict__ W2,   const float* __restrict__ b2,
    float* __restrict__ out)
{
    // LDS: all float2 = {batch0, batch1}
    __shared__ __align__(16) float2 smem[1050];
    float2* xbuf  = smem;        // [3][50] ring, slot = t % 3
    float2* h1buf = smem + 150;  // [2][50] slot = t & 1
    float2* h2buf = smem + 250;  // [2][50]
    float2* h3buf = smem + 350;  // [2][50]
    float2* gbuf  = smem + 450;  // [3][200] activated gates (i,f,g,o)

    const int tid = threadIdx.x;
    const int b0  = blockIdx.x * 2;

    // zero LDS (initial h/c state = 0)
    for (int i = tid; i < 1050; i += 768) smem[i] = make_float2(0.f, 0.f);
    __syncthreads();

    // ---- role setup; wreg shared across disjoint roles to cap VGPRs ----
    float wreg[100];
    float biasr = 0.f;
    int   lyr = 0, g = 0;
    float a2 = 1.f, cc = 0.f;          // activation: b*sigm(a*x)+c
    int   ob = 0, ok = 0;              // out-proj role
    int   pb = 0, pj = 0;              // prefetch role
    float2 c1 = make_float2(0.f, 0.f); // L1 cell (threads 0-49)
    float  xstage = 0.f;               // prefetch staging reg

    if (tid < 600) {                   // gate threads: lyr in {0,1,2}, gate g
        lyr = tid / 200; g = tid % 200;
        const float* Wih = (lyr == 0) ? Wih1 : (lyr == 1 ? Wih2 : Wih3);
        const float* Whh = (lyr == 0) ? Whh1 : (lyr == 1 ? Whh2 : Whh3);
        const float* bi  = (lyr == 0) ? bih1 : (lyr == 1 ? bih2 : bih3);
        const float* bh  = (lyr == 0) ? bhh1 : (lyr == 1 ? bhh2 : bhh3);
        #pragma unroll
        for (int k = 0; k < 50; k++) wreg[k]      = Wih[g * 50 + k];
        #pragma unroll
        for (int k = 0; k < 50; k++) wreg[50 + k] = Whh[g * 50 + k];
        biasr = bi[g] + bh[g];
        if (g / 50 == 2) { a2 = 2.f; cc = -1.f; }  // 'g' gate -> tanh
    } else if (tid >= 640 && tid < 656) {          // out-proj: 8 outs x 2 batch
        int idx = tid - 640; ob = idx >> 3; ok = idx & 7;
        #pragma unroll
        for (int j = 0; j < 50; j++) wreg[j] = W2[ok * 50 + j];
        biasr = b2[ok];
    } else if (tid >= 656 && tid < 756) {          // linear1 prefetch: 50 j x 2 b
        int idx = tid - 656; pb = idx / 50; pj = idx % 50;
        #pragma unroll
        for (int k = 0; k < 20; k++) wreg[k] = W1[pj * 20 + k];
        biasr = b1[pj];
        // prologue: hid(0) -> xbuf[0], hid(1) -> xbuf[1]
        const float* xp = x + ((size_t)(b0 + pb)) * T_SEQ * IN_DIM;
        float h0 = biasr, h1v = biasr;
        #pragma unroll
        for (int k = 0; k < 20; k++) h0  = fmaf(wreg[k], xp[k], h0);
        #pragma unroll
        for (int k = 0; k < 20; k++) h1v = fmaf(wreg[k], xp[IN_DIM + k], h1v);
        ((float*)(xbuf +      pj))[pb] = h0;
        ((float*)(xbuf + 50 + pj))[pb] = h1v;
    }
    __syncthreads();

    for (int s = 0; s < T_SEQ + 3; ++s) {
        const int p = s & 1, pm = p ^ 1, q3 = s % 3;

        // ================= phase A =================
        if (tid < 600) {
            const int tl = s - lyr;
            if (tl >= 0 && tl < T_SEQ) {
                const float2* vA;
                const float2* vB;
                if (lyr == 0)      { vA = xbuf  + q3 * 50; vB = h1buf + pm * 50; }
                else if (lyr == 1) { vA = h1buf + pm * 50; vB = h2buf + p  * 50; }
                else               { vA = h2buf + p  * 50; vB = h3buf + pm * 50; }
                float ax = biasr, ay = biasr, bx = 0.f, by = 0.f;
                const float4* A4 = (const float4*)vA;
                const float4* B4 = (const float4*)vB;
                #pragma unroll
                for (int k = 0; k < 25; k++) {
                    float4 v = A4[k];
                    ax = fmaf(wreg[2 * k],     v.x, ax);
                    ay = fmaf(wreg[2 * k],     v.y, ay);
                    bx = fmaf(wreg[2 * k + 1], v.z, bx);
                    by = fmaf(wreg[2 * k + 1], v.w, by);
                }
                #pragma unroll
                for (int k = 0; k < 25; k++) {
                    float4 v = B4[k];
                    ax = fmaf(wreg[50 + 2 * k],     v.x, ax);
                    ay = fmaf(wreg[50 + 2 * k],     v.y, ay);
                    bx = fmaf(wreg[50 + 2 * k + 1], v.z, bx);
                    by = fmaf(wreg[50 + 2 * k + 1], v.w, by);
                }
                float px_ = ax + bx, py_ = ay + by;
                float2 r;
                r.x = fmaf(a2, sigm(a2 * px_), cc);
                r.y = fmaf(a2, sigm(a2 * py_), cc);
                gbuf[lyr * NGATE + g] = r;
            }
        } else if (tid >= 640 && tid < 656) {          // out(t = s-3)
            if (s >= 3) {
                const int t = s - 3;
                const float* h3v = (const float*)(h3buf + pm * 50);
                float acc = biasr;
                #pragma unroll
                for (int j = 0; j < 50; j++)
                    acc = fmaf(wreg[j], h3v[2 * j + ob], acc);
                out[((size_t)(b0 + ob) * T_SEQ + t) * OUT_DIM + ok] = acc;
            }
        } else if (tid >= 656 && tid < 756) {          // hid(s+2) load+dot
            if (s + 2 < T_SEQ) {
                const float* xp = x + (((size_t)(b0 + pb)) * T_SEQ + (s + 2)) * IN_DIM;
                float hv = biasr;
                #pragma unroll
                for (int k = 0; k < 20; k++) hv = fmaf(wreg[k], xp[k], hv);
                xstage = hv;
            }
        }
        __syncthreads();

        // ================= phase B (combines) =================
        if (tid < 50) {                                // L1 combine, t = s
            if (s < T_SEQ) {
                float2 gi = gbuf[tid],       gf = gbuf[50 + tid];
                float2 gg = gbuf[100 + tid], go = gbuf[150 + tid];
                c1.x = fmaf(gf.x, c1.x, gi.x * gg.x);
                c1.y = fmaf(gf.y, c1.y, gi.y * gg.y);
                float2 h;
                h.x = go.x * tanh_f(c1.x);
                h.y = go.y * tanh_f(c1.y);
                h1buf[p * 50 + tid] = h;
            }
        } else if (tid >= 64 && tid < 114) {           // L3 then L2 combine
            const int j = tid - 64;
            float2 cn3 = make_float2(0.f, 0.f);        // c2(t2-1); 0 if L3 idle (s==1)
            if (s >= 2 && s <= T_SEQ + 1) {            // L3, t3 = s-2 (c3 == 0)
                float2 gi = gbuf[400 + j], gg = gbuf[500 + j], go = gbuf[550 + j];
                cn3.x = gi.x * gg.x;                   // f3 * c3 drops (c3=0)
                cn3.y = gi.y * gg.y;
                float2 h;
                h.x = go.x * tanh_f(cn3.x);
                h.y = go.y * tanh_f(cn3.y);
                h3buf[p * 50 + j] = h;                 // (s-2)&1 == p
            }
            if (s >= 1 && s <= T_SEQ) {                // L2, t2 = s-1
                float2 gi = gbuf[200 + j], gf = gbuf[250 + j];
                float2 gg = gbuf[300 + j], go = gbuf[350 + j];
                float2 c2n;                            // L2's own cell: dead after h2
                c2n.x = fmaf(gf.x, cn3.x, gi.x * gg.x);
                c2n.y = fmaf(gf.y, cn3.y, gi.y * gg.y);
                float2 h;
                h.x = go.x * tanh_f(c2n.x);
                h.y = go.y * tanh_f(c2n.y);
                h2buf[pm * 50 + j] = h;
            }
        } else if (tid >= 656 && tid < 756) {          // commit hid(s+2)
            if (s + 2 < T_SEQ) {
                ((float*)(xbuf + ((s + 2) % 3) * 50 + pj))[pb] = xstage;
            }
        }
        __syncthreads();
    }
}

extern "C" void kernel_launch(void* const* d_in, const int* in_sizes, int n_in,
                              void* d_out, int out_size, void* d_ws, size_t ws_size,
                              hipStream_t stream) {
    const float* x    = (const float*)d_in[0];
    const float* W1   = (const float*)d_in[1];
    const float* b1   = (const float*)d_in[2];
    const float* Wih1 = (const float*)d_in[3];
    const float* Whh1 = (const float*)d_in[4];
    const float* bih1 = (const float*)d_in[5];
    const float* bhh1 = (const float*)d_in[6];
    const float* Wih2 = (const float*)d_in[7];
    const float* Whh2 = (const float*)d_in[8];
    const float* bih2 = (const float*)d_in[9];
    const float* bhh2 = (const float*)d_in[10];
    const float* Wih3 = (const float*)d_in[11];
    const float* Whh3 = (const float*)d_in[12];
    const float* bih3 = (const float*)d_in[13];
    const float* bhh3 = (const float*)d_in[14];
    const float* W2   = (const float*)d_in[15];
    const float* b2   = (const float*)d_in[16];
    float* out = (float*)d_out;

    dim3 grid(256), block(768);   // 512 batch / 2 per block; 12 waves/block
    lstm_net_kernel<<<grid, block, 0, stream>>>(
        x, W1, b1, Wih1, Whh1, bih1, bhh1, Wih2, Whh2, bih2, bhh2,
        Wih3, Whh3, bih3, bhh3, W2, b2, out);
}